// Round 7
// baseline (527.287 us; speedup 1.0000x reference)
//
#include <hip/hip_runtime.h>
#include <hip/hip_bf16.h>
#include <math.h>

#define L_SEQ 2048
#define B_SZ 2
#define D_MODEL 768
#define D_INNER 1536
#define D_STATE 16
#define DT_RANK 48
#define TC 64
#define NC (L_SEQ / TC)          // 32 chunks
#define NDG (D_INNER / 256)      // 6 d-groups
#define NSPL 4
#define KCH (D_INNER / NSPL)     // 384

typedef short bf16x8 __attribute__((ext_vector_type(8)));
typedef float f32x4 __attribute__((ext_vector_type(4)));

#define GLOAD16(g, l) __builtin_amdgcn_global_load_lds( \
    (const __attribute__((address_space(1))) unsigned*)(g), \
    (__attribute__((address_space(3))) unsigned*)(l), 16, 0, 0)

static __device__ __forceinline__ float siluf(float v) {
  return v / (1.0f + __expf(-v));
}
static __device__ __forceinline__ float softplusf(float v) {
  return fmaxf(v, 0.0f) + log1pf(__expf(-fabsf(v)));
}
static __device__ __forceinline__ unsigned short f2bf_rn(float v) {
  unsigned u = __float_as_uint(v);
  u = (u + 0x7fff + ((u >> 16) & 1)) >> 16;
  return (unsigned short)u;
}

// -------- fused fp32 -> bf16 hi/lo conversion for all 5 tensors -----------
__global__ __launch_bounds__(256) void cvt_all(
    const float* __restrict__ s_h,  unsigned short* __restrict__ hh,  unsigned short* __restrict__ hl,
    const float* __restrict__ s_w0, unsigned short* __restrict__ w0h, unsigned short* __restrict__ w0l,
    const float* __restrict__ s_w1, unsigned short* __restrict__ w1h, unsigned short* __restrict__ w1l,
    const float* __restrict__ s_o0, unsigned short* __restrict__ o0h, unsigned short* __restrict__ o0l,
    const float* __restrict__ s_o1, unsigned short* __restrict__ o1h, unsigned short* __restrict__ o1l)
{
  long j = (long)blockIdx.x * 256 + threadIdx.x;   // float4 index
  const long N0 = 786432, N1 = 589824, N2 = 589824, N3 = 294912;
  const float* src; unsigned short *dh, *dl;
  if (j < N0) { src = s_h; dh = hh; dl = hl; }
  else if ((j -= N0) < N1) { src = s_w0; dh = w0h; dl = w0l; }
  else if ((j -= N1) < N2) { src = s_w1; dh = w1h; dl = w1l; }
  else if ((j -= N2) < N3) { src = s_o0; dh = o0h; dl = o0l; }
  else { j -= N3; src = s_o1; dh = o1h; dl = o1l; }
  float4 v = ((const float4*)src)[j];
  float vv[4] = {v.x, v.y, v.z, v.w};
  unsigned short h4[4], l4[4];
  #pragma unroll
  for (int e = 0; e < 4; ++e) {
    unsigned short hv = f2bf_rn(vv[e]);
    h4[e] = hv;
    l4[e] = f2bf_rn(vv[e] - __uint_as_float((unsigned)hv << 16));
  }
  uint2 ph, pl;
  ph.x = (unsigned)h4[0] | ((unsigned)h4[1] << 16);
  ph.y = (unsigned)h4[2] | ((unsigned)h4[3] << 16);
  pl.x = (unsigned)l4[0] | ((unsigned)l4[1] << 16);
  pl.y = (unsigned)l4[2] | ((unsigned)l4[3] << 16);
  *(uint2*)&dh[j * 4] = ph;
  *(uint2*)&dl[j * 4] = pl;
}

// -------- in_proj: bf16-plane MFMA GEMM, global_load_lds staging ----------
__global__ __launch_bounds__(256) void gemm_inproj(
    const unsigned short* __restrict__ hh, const unsigned short* __restrict__ hl,
    const unsigned short* __restrict__ w0h, const unsigned short* __restrict__ w0l,
    const unsigned short* __restrict__ w1h, const unsigned short* __restrict__ w1l,
    float* __restrict__ xpre, float* __restrict__ zbuf)
{
  __shared__ unsigned short Ah[128 * 32], Al[128 * 32];
  __shared__ unsigned short Wh[128 * 32], Wl[128 * 32];
  const long S1 = (long)B_SZ * L_SEQ * D_INNER;
  const int tid = threadIdx.x;
  const int lane = tid & 63, w = tid >> 6;
  int bid = blockIdx.x;
  int swz = (bid & 7) * 192 + (bid >> 3);
  int dir = swz / 768;
  int rem = swz - dir * 768;
  int mb = rem / 24, nb = rem - (rem / 24) * 24;
  const int m0 = mb * 128, n0 = nb * 128;
  const unsigned short* Whp = dir ? w1h : w0h;
  const unsigned short* Wlp = dir ? w1l : w0l;
  const int ksl = (lane & 3) ^ ((lane >> 3) & 3);
  long aoff[2], woff[2];
  int ldsc[2];
  #pragma unroll
  for (int qq = 0; qq < 2; ++qq) {
    int cq = w * 2 + qq;
    int r = cq * 16 + (lane >> 2);
    int mr = m0 + r;
    int row = dir ? ((mr & ~(L_SEQ - 1)) | ((L_SEQ - 1) - (mr & (L_SEQ - 1)))) : mr;
    aoff[qq] = (long)row * D_MODEL + 8 * ksl;
    woff[qq] = (long)(n0 + r) * D_MODEL + 8 * ksl;
    ldsc[qq] = cq * 512;
  }
  f32x4 acc[4][4];
  #pragma unroll
  for (int i = 0; i < 4; ++i)
    #pragma unroll
    for (int j = 0; j < 4; ++j) acc[i][j] = (f32x4){0.f, 0.f, 0.f, 0.f};
  const int fr = lane & 15, sl = lane >> 4;
  const int wr = w >> 1, wc = w & 1;
  int roffA[4], roffW[4];
  #pragma unroll
  for (int f = 0; f < 4; ++f) {
    int rA = wr * 64 + f * 16 + fr;
    roffA[f] = rA * 32 + ((sl ^ ((rA >> 1) & 3)) * 8);
    int rW = wc * 64 + f * 16 + fr;
    roffW[f] = rW * 32 + ((sl ^ ((rW >> 1) & 3)) * 8);
  }
  for (int k0 = 0; k0 < D_MODEL; k0 += 32) {
    __syncthreads();
    #pragma unroll
    for (int qq = 0; qq < 2; ++qq) {
      GLOAD16(hh + aoff[qq] + k0, &Ah[ldsc[qq]]);
      GLOAD16(hl + aoff[qq] + k0, &Al[ldsc[qq]]);
      GLOAD16(Whp + woff[qq] + k0, &Wh[ldsc[qq]]);
      GLOAD16(Wlp + woff[qq] + k0, &Wl[ldsc[qq]]);
    }
    __syncthreads();
    bf16x8 afh[4], afl[4];
    #pragma unroll
    for (int f = 0; f < 4; ++f) {
      afh[f] = *(const bf16x8*)&Ah[roffA[f]];
      afl[f] = *(const bf16x8*)&Al[roffA[f]];
    }
    #pragma unroll
    for (int fj = 0; fj < 4; ++fj) {
      bf16x8 wfh = *(const bf16x8*)&Wh[roffW[fj]];
      bf16x8 wfl = *(const bf16x8*)&Wl[roffW[fj]];
      #pragma unroll
      for (int fi = 0; fi < 4; ++fi) {
        acc[fi][fj] = __builtin_amdgcn_mfma_f32_16x16x32_bf16(afh[fi], wfh, acc[fi][fj], 0, 0, 0);
        acc[fi][fj] = __builtin_amdgcn_mfma_f32_16x16x32_bf16(afh[fi], wfl, acc[fi][fj], 0, 0, 0);
        acc[fi][fj] = __builtin_amdgcn_mfma_f32_16x16x32_bf16(afl[fi], wfh, acc[fi][fj], 0, 0, 0);
      }
    }
  }
  float* xq = xpre + (long)dir * S1;
  float* zq = zbuf + (long)dir * S1;
  const int fcol = lane & 15, rgrp = lane >> 4;
  #pragma unroll
  for (int fi = 0; fi < 4; ++fi) {
    #pragma unroll
    for (int j = 0; j < 4; ++j) {
      int row = m0 + wr * 64 + fi * 16 + rgrp * 4 + j;
      #pragma unroll
      for (int fj = 0; fj < 4; ++fj) {
        int n = n0 + wc * 64 + fj * 16 + fcol;
        float v = acc[fi][fj][j];
        if (n < D_INNER) xq[(long)row * D_INNER + n] = v;
        else             zq[(long)row * D_INNER + (n - D_INNER)] = v;
      }
    }
  }
}

// -------- out_proj: all-plane MFMA; split-(dir,K); GLOAD16 staging --------
// grid: 768 = 2 dir x 2 ks x 32 mb x 6 nb, XCD-swizzled.
__global__ __launch_bounds__(256) void gemm_outproj_pl(
    const unsigned short* __restrict__ yh, const unsigned short* __restrict__ yl,
    const unsigned short* __restrict__ o0h, const unsigned short* __restrict__ o0l,
    const unsigned short* __restrict__ o1h, const unsigned short* __restrict__ o1l,
    float* __restrict__ partial)   // [4][4096][768], plane = dir*2+ks
{
  __shared__ unsigned short Ah[128 * 32], Al[128 * 32];
  __shared__ unsigned short Wh[128 * 32], Wl[128 * 32];
  const long S1 = (long)B_SZ * L_SEQ * D_INNER;
  const int tid = threadIdx.x;
  const int lane = tid & 63, w = tid >> 6;
  int bid = blockIdx.x;
  int swz = (bid & 7) * 96 + (bid >> 3);
  int dir = swz / 384;
  int r1 = swz - dir * 384;
  int ks = r1 / 192;
  int r2 = r1 - ks * 192;
  int mb = r2 / 6, nb = r2 - (r2 / 6) * 6;
  const int m0 = mb * 128, n0 = nb * 128;
  const int kbase = ks * (D_INNER / 2);
  const unsigned short* Ahp = yh + (long)dir * S1;
  const unsigned short* Alp = yl + (long)dir * S1;
  const unsigned short* Whp = dir ? o1h : o0h;
  const unsigned short* Wlp = dir ? o1l : o0l;
  const int ksl = (lane & 3) ^ ((lane >> 3) & 3);
  long aoff[2], woff[2];
  int ldsc[2];
  #pragma unroll
  for (int qq = 0; qq < 2; ++qq) {
    int cq = w * 2 + qq;
    int r = cq * 16 + (lane >> 2);
    int mr = m0 + r;
    int row = dir ? ((mr & ~(L_SEQ - 1)) | ((L_SEQ - 1) - (mr & (L_SEQ - 1)))) : mr;
    aoff[qq] = (long)row * D_INNER + 8 * ksl + kbase;
    woff[qq] = (long)(n0 + r) * D_INNER + 8 * ksl + kbase;
    ldsc[qq] = cq * 512;
  }
  f32x4 acc[4][4];
  #pragma unroll
  for (int i = 0; i < 4; ++i)
    #pragma unroll
    for (int j = 0; j < 4; ++j) acc[i][j] = (f32x4){0.f, 0.f, 0.f, 0.f};
  const int fr = lane & 15, sl = lane >> 4;
  const int wr = w >> 1, wc = w & 1;
  int roffA[4], roffW[4];
  #pragma unroll
  for (int f = 0; f < 4; ++f) {
    int rA = wr * 64 + f * 16 + fr;
    roffA[f] = rA * 32 + ((sl ^ ((rA >> 1) & 3)) * 8);
    int rW = wc * 64 + f * 16 + fr;
    roffW[f] = rW * 32 + ((sl ^ ((rW >> 1) & 3)) * 8);
  }
  for (int k0 = 0; k0 < D_INNER / 2; k0 += 32) {
    __syncthreads();
    #pragma unroll
    for (int qq = 0; qq < 2; ++qq) {
      GLOAD16(Ahp + aoff[qq] + k0, &Ah[ldsc[qq]]);
      GLOAD16(Alp + aoff[qq] + k0, &Al[ldsc[qq]]);
      GLOAD16(Whp + woff[qq] + k0, &Wh[ldsc[qq]]);
      GLOAD16(Wlp + woff[qq] + k0, &Wl[ldsc[qq]]);
    }
    __syncthreads();
    bf16x8 afh[4], afl[4];
    #pragma unroll
    for (int f = 0; f < 4; ++f) {
      afh[f] = *(const bf16x8*)&Ah[roffA[f]];
      afl[f] = *(const bf16x8*)&Al[roffA[f]];
    }
    #pragma unroll
    for (int fj = 0; fj < 4; ++fj) {
      bf16x8 wfh = *(const bf16x8*)&Wh[roffW[fj]];
      bf16x8 wfl = *(const bf16x8*)&Wl[roffW[fj]];
      #pragma unroll
      for (int fi = 0; fi < 4; ++fi) {
        acc[fi][fj] = __builtin_amdgcn_mfma_f32_16x16x32_bf16(afh[fi], wfh, acc[fi][fj], 0, 0, 0);
        acc[fi][fj] = __builtin_amdgcn_mfma_f32_16x16x32_bf16(afh[fi], wfl, acc[fi][fj], 0, 0, 0);
        acc[fi][fj] = __builtin_amdgcn_mfma_f32_16x16x32_bf16(afl[fi], wfh, acc[fi][fj], 0, 0, 0);
      }
    }
  }
  float* P = partial + (long)(dir * 2 + ks) * (B_SZ * L_SEQ) * D_MODEL;
  const int fcol = lane & 15, rgrp = lane >> 4;
  #pragma unroll
  for (int fi = 0; fi < 4; ++fi) {
    #pragma unroll
    for (int j = 0; j < 4; ++j) {
      int row = m0 + wr * 64 + fi * 16 + rgrp * 4 + j;
      #pragma unroll
      for (int fj = 0; fj < 4; ++fj) {
        int n = n0 + wc * 64 + fj * 16 + fcol;
        P[(long)row * D_MODEL + n] = acc[fi][fj][j];
      }
    }
  }
}

__global__ __launch_bounds__(256) void outproj_reduce(
    const float* __restrict__ partial, float* __restrict__ out)
{
  long i = (long)blockIdx.x * 256 + threadIdx.x;   // float4 index
  const long plane4 = (long)B_SZ * L_SEQ * D_MODEL / 4;  // 786432
  float4 a = ((const float4*)partial)[i];
  float4 b = ((const float4*)partial)[i + plane4];
  float4 c = ((const float4*)partial)[i + 2 * plane4];
  float4 d = ((const float4*)partial)[i + 3 * plane4];
  float4 s;
  s.x = (a.x + b.x) + (c.x + d.x);
  s.y = (a.y + b.y) + (c.y + d.y);
  s.z = (a.z + b.z) + (c.z + d.z);
  s.w = (a.w + b.w) + (c.w + d.w);
  ((float4*)out)[i] = s;
}

// ---------------- xproj: split-K tall-skinny GEMM (N=80) ------------------
__global__ __launch_bounds__(256) void xproj_splitk(
    const float* __restrict__ X,
    const float* __restrict__ xproj_f, const float* __restrict__ xproj_r,
    float* __restrict__ partial)
{
  const int tid = threadIdx.x;
  const int m0 = blockIdx.x * 64;
  const int kz = blockIdx.y;
  const int dir = blockIdx.z;
  const float* W = dir ? xproj_r : xproj_f;
  const float* A = X + (long)dir * B_SZ * L_SEQ * D_INNER;
  __shared__ float As[16][65];
  __shared__ float Ws[16][81];
  const int lk = tid & 15, lr = tid >> 4;
  const int tx = tid & 15, ty = tid >> 4;
  float acc[4][5] = {};
  const int kbase = kz * KCH;
  for (int k0 = 0; k0 < KCH; k0 += 16) {
    #pragma unroll
    for (int i = 0; i < 4; ++i)
      As[lk][lr + 16 * i] = A[(long)(m0 + lr + 16 * i) * D_INNER + kbase + k0 + lk];
    for (int r = lr; r < 80; r += 16)
      Ws[lk][r] = W[(long)r * D_INNER + kbase + k0 + lk];
    __syncthreads();
    #pragma unroll
    for (int kk = 0; kk < 16; ++kk) {
      float a[4], b[5];
      #pragma unroll
      for (int i = 0; i < 4; ++i) a[i] = As[kk][ty + 16 * i];
      #pragma unroll
      for (int j = 0; j < 5; ++j) b[j] = Ws[kk][tx * 5 + j];
      #pragma unroll
      for (int i = 0; i < 4; ++i)
        #pragma unroll
        for (int j = 0; j < 5; ++j) acc[i][j] = fmaf(a[i], b[j], acc[i][j]);
    }
    __syncthreads();
  }
  float* P = partial + (((long)dir * NSPL + kz) * (B_SZ * L_SEQ) + m0) * 80;
  #pragma unroll
  for (int i = 0; i < 4; ++i)
    #pragma unroll
    for (int j = 0; j < 5; ++j)
      P[(long)(ty + 16 * i) * 80 + tx * 5 + j] = acc[i][j];
}

__global__ __launch_bounds__(256) void xproj_reduce(
    const float* __restrict__ partial, float* __restrict__ dbl)
{
  long idx = (long)blockIdx.x * 256 + threadIdx.x;
  const long plane = (long)B_SZ * L_SEQ * 80;
  long dir = idx / plane;
  long rc = idx % plane;
  const float* P = partial + dir * NSPL * plane + rc;
  float s = 0.f;
  #pragma unroll
  for (int z = 0; z < NSPL; ++z) s += P[z * plane];
  dbl[idx] = s;
}

// -------- causal depthwise conv (w=4) + bias + silu, float4 ---------------
__global__ __launch_bounds__(256) void conv_silu_v4(
    const float* __restrict__ xpre,
    const float* __restrict__ w_f, const float* __restrict__ b_f,
    const float* __restrict__ w_r, const float* __restrict__ b_r,
    float* __restrict__ xconv)
{
  long i4 = (long)blockIdx.x * 256 + threadIdx.x;
  const long total4 = 2L * B_SZ * L_SEQ * D_INNER / 4;
  if (i4 >= total4) return;
  long idx = i4 * 4;
  int d0 = (int)(idx % D_INNER);
  long r = idx / D_INNER;
  int t = (int)(r & (L_SEQ - 1));
  const float* w  = (r >> 12) ? w_r : w_f;
  const float* cb = (r >> 12) ? b_r : b_f;
  float4 a = *(const float4*)&cb[d0];
  float4 wc[4];
  #pragma unroll
  for (int i = 0; i < 4; ++i) wc[i] = *(const float4*)&w[(d0 + i) * 4];
  #pragma unroll
  for (int k = 0; k < 4; ++k) {
    if (t - 3 + k >= 0) {
      float4 xv = *(const float4*)&xpre[(r - 3 + k) * D_INNER + d0];
      a.x = fmaf(((const float*)&wc[0])[k], xv.x, a.x);
      a.y = fmaf(((const float*)&wc[1])[k], xv.y, a.y);
      a.z = fmaf(((const float*)&wc[2])[k], xv.z, a.z);
      a.w = fmaf(((const float*)&wc[3])[k], xv.w, a.w);
    }
  }
  a.x = siluf(a.x); a.y = siluf(a.y); a.z = siluf(a.z); a.w = siluf(a.w);
  *(float4*)&xconv[idx] = a;
}

// -------- fused dtproj + selective-scan pass 1 (local S, P) ---------------
__global__ __launch_bounds__(256) void scan_mega1(
    const float* __restrict__ x, const float* __restrict__ dbl,
    const float* __restrict__ dtw_f, const float* __restrict__ dtw_r,
    const float* __restrict__ dtb_f, const float* __restrict__ dtb_r,
    const float* __restrict__ A_log_f, const float* __restrict__ A_log_r,
    float* __restrict__ stateS, float* __restrict__ stateP)
{
  const int tid = threadIdx.x;
  const int chunk = blockIdx.x / NDG;
  const int d = (blockIdx.x % NDG) * 256 + tid;
  const int b = blockIdx.y, dir = blockIdx.z;
  const float* A_log = dir ? A_log_r : A_log_f;
  const float* dtw   = dir ? dtw_r : dtw_f;
  const float dtbv   = (dir ? dtb_r : dtb_f)[d];
  float wreg[48];
  #pragma unroll
  for (int q = 0; q < 12; ++q)
    *(float4*)&wreg[q * 4] = *(const float4*)&dtw[d * DT_RANK + q * 4];
  float Arow[D_STATE];
  #pragma unroll
  for (int n = 0; n < D_STATE; ++n) Arow[n] = -expf(A_log[d * D_STATE + n]);
  float h[D_STATE], P[D_STATE];
  #pragma unroll
  for (int n = 0; n < D_STATE; ++n) { h[n] = 0.f; P[n] = 1.f; }
  const long rowbase = ((long)dir * B_SZ + b) * L_SEQ + (long)chunk * TC;
  for (int tj = 0; tj < TC; ++tj) {
    const float* br = dbl + (rowbase + tj) * 80;
    float dtacc = 0.f;
    #pragma unroll
    for (int q = 0; q < 12; ++q) {
      float4 v = *(const float4*)(br + q * 4);
      dtacc = fmaf(v.x, wreg[q * 4 + 0], dtacc);
      dtacc = fmaf(v.y, wreg[q * 4 + 1], dtacc);
      dtacc = fmaf(v.z, wreg[q * 4 + 2], dtacc);
      dtacc = fmaf(v.w, wreg[q * 4 + 3], dtacc);
    }
    float dtv = softplusf(dtacc + dtbv);
    float xv = x[(rowbase + tj) * D_INNER + d];
    float dtx = dtv * xv;
    float bc[D_STATE];
    #pragma unroll
    for (int q = 0; q < 4; ++q)
      *(float4*)&bc[q * 4] = *(const float4*)(br + 48 + q * 4);
    #pragma unroll
    for (int n = 0; n < D_STATE; ++n) {
      float dA = __expf(dtv * Arow[n]);
      P[n] *= dA;
      h[n] = fmaf(h[n], dA, dtx * bc[n]);
    }
  }
  long base = ((((long)dir * B_SZ + b) * NC + chunk) * D_INNER + d) * D_STATE;
  #pragma unroll
  for (int n = 0; n < D_STATE; ++n) { stateS[base + n] = h[n]; stateP[base + n] = P[n]; }
}

__global__ __launch_bounds__(256) void scan_fix(
    float* __restrict__ stateS, const float* __restrict__ stateP)
{
  const long idx = (long)blockIdx.x * 256 + threadIdx.x;
  const int DN = D_INNER * D_STATE;
  const long dirb = idx / DN;
  const int dn = (int)(idx % DN);
  long base = dirb * NC * DN + dn;
  float h = 0.f;
  for (int c = 0; c < NC; ++c) {
    long o = base + (long)c * DN;
    float S = stateS[o];
    float Pc = stateP[o];
    stateS[o] = h;
    h = fmaf(h, Pc, S);
  }
}

// -------- fused dtproj + scan pass 2 + gating + y->bf16 planes ------------
__global__ __launch_bounds__(256) void scan_mega2(
    const float* __restrict__ x, const float* __restrict__ dbl,
    const float* __restrict__ z,
    const float* __restrict__ dtw_f, const float* __restrict__ dtw_r,
    const float* __restrict__ dtb_f, const float* __restrict__ dtb_r,
    const float* __restrict__ A_log_f, const float* __restrict__ A_log_r,
    const float* __restrict__ Ds_f, const float* __restrict__ Ds_r,
    const float* __restrict__ stateS,
    unsigned short* __restrict__ yh, unsigned short* __restrict__ yl)
{
  const int tid = threadIdx.x;
  const int chunk = blockIdx.x / NDG;
  const int d = (blockIdx.x % NDG) * 256 + tid;
  const int b = blockIdx.y, dir = blockIdx.z;
  const float* A_log = dir ? A_log_r : A_log_f;
  const float* dtw   = dir ? dtw_r : dtw_f;
  const float dtbv   = (dir ? dtb_r : dtb_f)[d];
  const float Dd     = (dir ? Ds_r : Ds_f)[d];
  float wreg[48];
  #pragma unroll
  for (int q = 0; q < 12; ++q)
    *(float4*)&wreg[q * 4] = *(const float4*)&dtw[d * DT_RANK + q * 4];
  float Arow[D_STATE];
  #pragma unroll
  for (int n = 0; n < D_STATE; ++n) Arow[n] = -expf(A_log[d * D_STATE + n]);
  float h[D_STATE];
  long sbase = ((((long)dir * B_SZ + b) * NC + chunk) * D_INNER + d) * D_STATE;
  #pragma unroll
  for (int n = 0; n < D_STATE; ++n) h[n] = stateS[sbase + n];
  const long rowbase = ((long)dir * B_SZ + b) * L_SEQ + (long)chunk * TC;
  for (int tj = 0; tj < TC; ++tj) {
    const float* br = dbl + (rowbase + tj) * 80;
    float dtacc = 0.f;
    #pragma unroll
    for (int q = 0; q < 12; ++q) {
      float4 v = *(const float4*)(br + q * 4);
      dtacc = fmaf(v.x, wreg[q * 4 + 0], dtacc);
      dtacc = fmaf(v.y, wreg[q * 4 + 1], dtacc);
      dtacc = fmaf(v.z, wreg[q * 4 + 2], dtacc);
      dtacc = fmaf(v.w, wreg[q * 4 + 3], dtacc);
    }
    float dtv = softplusf(dtacc + dtbv);
    long off = (rowbase + tj) * D_INNER + d;
    float xv = x[off];
    float zv = z[off];
    float dtx = dtv * xv;
    float bc[2 * D_STATE];
    #pragma unroll
    for (int q = 0; q < 8; ++q)
      *(float4*)&bc[q * 4] = *(const float4*)(br + 48 + q * 4);
    float y = 0.f;
    #pragma unroll
    for (int n = 0; n < D_STATE; ++n) {
      float dA = __expf(dtv * Arow[n]);
      h[n] = fmaf(h[n], dA, dtx * bc[n]);
      y = fmaf(h[n], bc[16 + n], y);
    }
    y = fmaf(xv, Dd, y);
    y *= siluf(zv);
    unsigned short hv = f2bf_rn(y);
    yh[off] = hv;
    yl[off] = f2bf_rn(y - __uint_as_float((unsigned)hv << 16));
  }
}

extern "C" void kernel_launch(void* const* d_in, const int* in_sizes, int n_in,
                              void* d_out, int out_size, void* d_ws, size_t ws_size,
                              hipStream_t stream) {
  const float* h        = (const float*)d_in[0];
  const float* in_proj[2] = {(const float*)d_in[1], (const float*)d_in[10]};
  const float* conv_w[2]  = {(const float*)d_in[2], (const float*)d_in[11]};
  const float* conv_b[2]  = {(const float*)d_in[3], (const float*)d_in[12]};
  const float* xproj[2]   = {(const float*)d_in[4], (const float*)d_in[13]};
  const float* dtw[2]     = {(const float*)d_in[5], (const float*)d_in[14]};
  const float* dtb[2]     = {(const float*)d_in[6], (const float*)d_in[15]};
  const float* A_log[2]   = {(const float*)d_in[7], (const float*)d_in[16]};
  const float* Dsk[2]     = {(const float*)d_in[8], (const float*)d_in[17]};
  const float* outp[2]    = {(const float*)d_in[9], (const float*)d_in[18]};
  float* out = (float*)d_out;
  float* ws = (float*)d_ws;

  const long S1 = (long)B_SZ * L_SEQ * D_INNER;   // 6,291,456
  const int M = B_SZ * L_SEQ;                     // 4096
  float* xpre  = ws;                 // [2][4096][1536]: x-preconv, then yh/yl planes
  float* zbuf  = ws + 2 * S1;        // z
  float* xconv = ws + 4 * S1;        // x (conv out), then out_proj partials
  float* dbl   = ws + 6 * S1;        // [2][4096][80]
  float* base4 = dbl + 2L * M * 80;

  // bf16 hi/lo planes (phase A); scan states / xproj partials overlay later
  unsigned short* hh  = (unsigned short*)base4;             // 3,145,728 each
  unsigned short* hl  = hh + 3145728;
  unsigned short* w0h = hl + 3145728;                       // 2,359,296 each
  unsigned short* w0l = w0h + 2359296;
  unsigned short* w1h = w0l + 2359296;
  unsigned short* w1l = w1h + 2359296;
  unsigned short* o0h = w1l + 2359296;                      // 1,179,648 each (live till end)
  unsigned short* o0l = o0h + 1179648;
  unsigned short* o1h = o0l + 1179648;
  unsigned short* o1l = o1h + 1179648;
  float* xpartial = base4;           // xproj partials overlay hh/hl (dead after in_proj)
  float* stS = base4;                // 3.15M fl
  float* stP = stS + 3145728;        // 3.15M fl (ends before o-planes)
  // y planes overlay xpre (dead after conv): yh needs 2*S1 ushorts, yl follows.
  // FIX (round 6 bug): yl = yh + 2*S1 (was +S1, which collided with yh[dir=1]).
  unsigned short* yh = (unsigned short*)xpre;               // [2][4096][1536] bf16
  unsigned short* yl = yh + 2 * S1;
  float* opartial = xconv;           // [4][4096][768] = 12.58M fl

  dim3 blk(256);

  // 0. pre-convert h + all GEMM weights to bf16 hi/lo planes
  cvt_all<<<dim3(9984), blk, 0, stream>>>(
      h, hh, hl, in_proj[0], w0h, w0l, in_proj[1], w1h, w1l,
      outp[0], o0h, o0l, outp[1], o1h, o1l);

  // 1. in_proj (both dirs) -> x (pre-conv) and z
  gemm_inproj<<<dim3(1536), blk, 0, stream>>>(hh, hl, w0h, w0l, w1h, w1l, xpre, zbuf);

  // 2. conv + silu
  conv_silu_v4<<<dim3((unsigned)(2 * S1 / 4 / 256)), blk, 0, stream>>>(
      xpre, conv_w[0], conv_b[0], conv_w[1], conv_b[1], xconv);

  // 3. xproj (split-K) -> dbl
  {
    dim3 grid(M / 64, NSPL, 2);
    xproj_splitk<<<grid, blk, 0, stream>>>(xconv, xproj[0], xproj[1], xpartial);
    long n = 2L * M * 80;
    xproj_reduce<<<dim3((unsigned)(n / 256)), blk, 0, stream>>>(xpartial, dbl);
  }
  // 4+5a. fused dtproj + scan pass 1
  {
    dim3 grid1(NC * NDG, B_SZ, 2);
    scan_mega1<<<grid1, blk, 0, stream>>>(xconv, dbl,
        dtw[0], dtw[1], dtb[0], dtb[1], A_log[0], A_log[1], stS, stP);
    long nfix = 2L * B_SZ * D_INNER * D_STATE;
    scan_fix<<<dim3((unsigned)(nfix / 256)), blk, 0, stream>>>(stS, stP);
    // 5b. fused dtproj + scan pass 2 + gating; y emitted as bf16 hi/lo planes
    scan_mega2<<<grid1, blk, 0, stream>>>(xconv, dbl, zbuf,
        dtw[0], dtw[1], dtb[0], dtb[1], A_log[0], A_log[1],
        Dsk[0], Dsk[1], stS, yh, yl);
  }
  // 6. out_proj: split-(dir,K) all-plane MFMA + reduce
  gemm_outproj_pl<<<dim3(768), blk, 0, stream>>>(yh, yl, o0h, o0l, o1h, o1l, opartial);
  outproj_reduce<<<dim3((unsigned)(M * (long)D_MODEL / 4 / 256)), blk, 0, stream>>>(opartial, out);
}

// Round 8
// 493.593 us; speedup vs baseline: 1.0683x; 1.0683x over previous
//
#include <hip/hip_runtime.h>
#include <hip/hip_bf16.h>
#include <math.h>

#define L_SEQ 2048
#define B_SZ 2
#define D_MODEL 768
#define D_INNER 1536
#define D_STATE 16
#define DT_RANK 48
#define TC 64
#define NC (L_SEQ / TC)          // 32 chunks
#define NDG (D_INNER / 256)      // 6 d-groups
#define NSPL 4
#define KCH (D_INNER / NSPL)     // 384

typedef short bf16x8 __attribute__((ext_vector_type(8)));
typedef float f32x4 __attribute__((ext_vector_type(4)));

#define GLOAD16(g, l) __builtin_amdgcn_global_load_lds( \
    (const __attribute__((address_space(1))) unsigned*)(g), \
    (__attribute__((address_space(3))) unsigned*)(l), 16, 0, 0)

static __device__ __forceinline__ float siluf(float v) {
  return v / (1.0f + __expf(-v));
}
static __device__ __forceinline__ float softplusf(float v) {
  return fmaxf(v, 0.0f) + log1pf(__expf(-fabsf(v)));
}
static __device__ __forceinline__ unsigned short f2bf_rn(float v) {
  unsigned u = __float_as_uint(v);
  u = (u + 0x7fff + ((u >> 16) & 1)) >> 16;
  return (unsigned short)u;
}
static __device__ __forceinline__ float bf2f(unsigned short v) {
  return __uint_as_float((unsigned)v << 16);
}

// -------- fused fp32 -> bf16 hi/lo conversion for all 7 tensors -----------
__global__ __launch_bounds__(256) void cvt_all(
    const float* __restrict__ s_h,  unsigned short* __restrict__ hh,  unsigned short* __restrict__ hl,
    const float* __restrict__ s_w0, unsigned short* __restrict__ w0h, unsigned short* __restrict__ w0l,
    const float* __restrict__ s_w1, unsigned short* __restrict__ w1h, unsigned short* __restrict__ w1l,
    const float* __restrict__ s_o0, unsigned short* __restrict__ o0h, unsigned short* __restrict__ o0l,
    const float* __restrict__ s_o1, unsigned short* __restrict__ o1h, unsigned short* __restrict__ o1l,
    const float* __restrict__ s_x0, unsigned short* __restrict__ x0h, unsigned short* __restrict__ x0l,
    const float* __restrict__ s_x1, unsigned short* __restrict__ x1h, unsigned short* __restrict__ x1l)
{
  long j = (long)blockIdx.x * 256 + threadIdx.x;   // float4 index
  const long N0 = 786432, N1 = 589824, N2 = 589824, N3 = 294912, N4 = 294912, N5 = 30720;
  const float* src; unsigned short *dh, *dl;
  if (j < N0) { src = s_h; dh = hh; dl = hl; }
  else if ((j -= N0) < N1) { src = s_w0; dh = w0h; dl = w0l; }
  else if ((j -= N1) < N2) { src = s_w1; dh = w1h; dl = w1l; }
  else if ((j -= N2) < N3) { src = s_o0; dh = o0h; dl = o0l; }
  else if ((j -= N3) < N4) { src = s_o1; dh = o1h; dl = o1l; }
  else if ((j -= N4) < N5) { src = s_x0; dh = x0h; dl = x0l; }
  else { j -= N5; src = s_x1; dh = x1h; dl = x1l; }
  float4 v = ((const float4*)src)[j];
  float vv[4] = {v.x, v.y, v.z, v.w};
  unsigned short h4[4], l4[4];
  #pragma unroll
  for (int e = 0; e < 4; ++e) {
    unsigned short hv = f2bf_rn(vv[e]);
    h4[e] = hv;
    l4[e] = f2bf_rn(vv[e] - bf2f(hv));
  }
  uint2 ph, pl;
  ph.x = (unsigned)h4[0] | ((unsigned)h4[1] << 16);
  ph.y = (unsigned)h4[2] | ((unsigned)h4[3] << 16);
  pl.x = (unsigned)l4[0] | ((unsigned)l4[1] << 16);
  pl.y = (unsigned)l4[2] | ((unsigned)l4[3] << 16);
  *(uint2*)&dh[j * 4] = ph;
  *(uint2*)&dl[j * 4] = pl;
}

// -------- in_proj: bf16-plane MFMA GEMM, global_load_lds staging ----------
__global__ __launch_bounds__(256) void gemm_inproj(
    const unsigned short* __restrict__ hh, const unsigned short* __restrict__ hl,
    const unsigned short* __restrict__ w0h, const unsigned short* __restrict__ w0l,
    const unsigned short* __restrict__ w1h, const unsigned short* __restrict__ w1l,
    float* __restrict__ xpre, float* __restrict__ zbuf)
{
  __shared__ unsigned short Ah[128 * 32], Al[128 * 32];
  __shared__ unsigned short Wh[128 * 32], Wl[128 * 32];
  const long S1 = (long)B_SZ * L_SEQ * D_INNER;
  const int tid = threadIdx.x;
  const int lane = tid & 63, w = tid >> 6;
  int bid = blockIdx.x;
  int swz = (bid & 7) * 192 + (bid >> 3);
  int dir = swz / 768;
  int rem = swz - dir * 768;
  int mb = rem / 24, nb = rem - (rem / 24) * 24;
  const int m0 = mb * 128, n0 = nb * 128;
  const unsigned short* Whp = dir ? w1h : w0h;
  const unsigned short* Wlp = dir ? w1l : w0l;
  const int ksl = (lane & 3) ^ ((lane >> 3) & 3);
  long aoff[2], woff[2];
  int ldsc[2];
  #pragma unroll
  for (int qq = 0; qq < 2; ++qq) {
    int cq = w * 2 + qq;
    int r = cq * 16 + (lane >> 2);
    int mr = m0 + r;
    int row = dir ? ((mr & ~(L_SEQ - 1)) | ((L_SEQ - 1) - (mr & (L_SEQ - 1)))) : mr;
    aoff[qq] = (long)row * D_MODEL + 8 * ksl;
    woff[qq] = (long)(n0 + r) * D_MODEL + 8 * ksl;
    ldsc[qq] = cq * 512;
  }
  f32x4 acc[4][4];
  #pragma unroll
  for (int i = 0; i < 4; ++i)
    #pragma unroll
    for (int j = 0; j < 4; ++j) acc[i][j] = (f32x4){0.f, 0.f, 0.f, 0.f};
  const int fr = lane & 15, sl = lane >> 4;
  const int wr = w >> 1, wc = w & 1;
  int roffA[4], roffW[4];
  #pragma unroll
  for (int f = 0; f < 4; ++f) {
    int rA = wr * 64 + f * 16 + fr;
    roffA[f] = rA * 32 + ((sl ^ ((rA >> 1) & 3)) * 8);
    int rW = wc * 64 + f * 16 + fr;
    roffW[f] = rW * 32 + ((sl ^ ((rW >> 1) & 3)) * 8);
  }
  for (int k0 = 0; k0 < D_MODEL; k0 += 32) {
    __syncthreads();
    #pragma unroll
    for (int qq = 0; qq < 2; ++qq) {
      GLOAD16(hh + aoff[qq] + k0, &Ah[ldsc[qq]]);
      GLOAD16(hl + aoff[qq] + k0, &Al[ldsc[qq]]);
      GLOAD16(Whp + woff[qq] + k0, &Wh[ldsc[qq]]);
      GLOAD16(Wlp + woff[qq] + k0, &Wl[ldsc[qq]]);
    }
    __syncthreads();
    bf16x8 afh[4], afl[4];
    #pragma unroll
    for (int f = 0; f < 4; ++f) {
      afh[f] = *(const bf16x8*)&Ah[roffA[f]];
      afl[f] = *(const bf16x8*)&Al[roffA[f]];
    }
    #pragma unroll
    for (int fj = 0; fj < 4; ++fj) {
      bf16x8 wfh = *(const bf16x8*)&Wh[roffW[fj]];
      bf16x8 wfl = *(const bf16x8*)&Wl[roffW[fj]];
      #pragma unroll
      for (int fi = 0; fi < 4; ++fi) {
        acc[fi][fj] = __builtin_amdgcn_mfma_f32_16x16x32_bf16(afh[fi], wfh, acc[fi][fj], 0, 0, 0);
        acc[fi][fj] = __builtin_amdgcn_mfma_f32_16x16x32_bf16(afh[fi], wfl, acc[fi][fj], 0, 0, 0);
        acc[fi][fj] = __builtin_amdgcn_mfma_f32_16x16x32_bf16(afl[fi], wfh, acc[fi][fj], 0, 0, 0);
      }
    }
  }
  float* xq = xpre + (long)dir * S1;
  float* zq = zbuf + (long)dir * S1;
  const int fcol = lane & 15, rgrp = lane >> 4;
  #pragma unroll
  for (int fi = 0; fi < 4; ++fi) {
    #pragma unroll
    for (int j = 0; j < 4; ++j) {
      int row = m0 + wr * 64 + fi * 16 + rgrp * 4 + j;
      #pragma unroll
      for (int fj = 0; fj < 4; ++fj) {
        int n = n0 + wc * 64 + fj * 16 + fcol;
        float v = acc[fi][fj][j];
        if (n < D_INNER) xq[(long)row * D_INNER + n] = v;
        else             zq[(long)row * D_INNER + (n - D_INNER)] = v;
      }
    }
  }
}

// -------- xproj: plane MFMA, N=80 padded to 128, split-K x4 ---------------
// grid: 256 blocks = 2 dir x 4 kz x 32 mb (exactly one machine round).
__global__ __launch_bounds__(256) void xproj_mfma(
    const unsigned short* __restrict__ xh, const unsigned short* __restrict__ xl,
    const unsigned short* __restrict__ x0h, const unsigned short* __restrict__ x0l,
    const unsigned short* __restrict__ x1h, const unsigned short* __restrict__ x1l,
    float* __restrict__ partial)   // [2*NSPL][4096][80]
{
  __shared__ unsigned short Ah[128 * 32], Al[128 * 32];
  __shared__ unsigned short Wh[128 * 32], Wl[128 * 32];
  const long S1 = (long)B_SZ * L_SEQ * D_INNER;
  const int tid = threadIdx.x;
  const int lane = tid & 63, w = tid >> 6;
  int bid = blockIdx.x;
  int dir = bid >> 7;
  int kz = (bid >> 5) & 3;
  int mb = bid & 31;
  const int m0 = mb * 128;
  const int kbase = kz * KCH;
  const unsigned short* Ahp = xh + (long)dir * S1;
  const unsigned short* Alp = xl + (long)dir * S1;
  const unsigned short* Whp = dir ? x1h : x0h;
  const unsigned short* Wlp = dir ? x1l : x0l;
  const int ksl = (lane & 3) ^ ((lane >> 3) & 3);
  long aoff[2], woff[2];
  int ldsc[2], cqv[2];
  #pragma unroll
  for (int qq = 0; qq < 2; ++qq) {
    int cq = w * 2 + qq;
    int r = cq * 16 + (lane >> 2);
    aoff[qq] = (long)(m0 + r) * D_INNER + 8 * ksl + kbase;
    woff[qq] = (long)r * D_INNER + 8 * ksl + kbase;   // W plane rows 0..79 used
    ldsc[qq] = cq * 512;
    cqv[qq] = cq;
  }
  // zero LDS W rows 80..127 once (never overwritten: GLOAD16 only for rows<80)
  for (int i = tid; i < 48 * 32; i += 256) { Wh[80 * 32 + i] = 0; Wl[80 * 32 + i] = 0; }
  f32x4 acc[4][4];
  #pragma unroll
  for (int i = 0; i < 4; ++i)
    #pragma unroll
    for (int j = 0; j < 4; ++j) acc[i][j] = (f32x4){0.f, 0.f, 0.f, 0.f};
  const int fr = lane & 15, sl = lane >> 4;
  const int wr = w >> 1, wc = w & 1;
  int roffA[4], roffW[4];
  #pragma unroll
  for (int f = 0; f < 4; ++f) {
    int rA = wr * 64 + f * 16 + fr;
    roffA[f] = rA * 32 + ((sl ^ ((rA >> 1) & 3)) * 8);
    int rW = wc * 64 + f * 16 + fr;
    roffW[f] = rW * 32 + ((sl ^ ((rW >> 1) & 3)) * 8);
  }
  for (int k0 = 0; k0 < KCH; k0 += 32) {
    __syncthreads();
    #pragma unroll
    for (int qq = 0; qq < 2; ++qq) {
      GLOAD16(Ahp + aoff[qq] + k0, &Ah[ldsc[qq]]);
      GLOAD16(Alp + aoff[qq] + k0, &Al[ldsc[qq]]);
      if (cqv[qq] < 5) {
        GLOAD16(Whp + woff[qq] + k0, &Wh[ldsc[qq]]);
        GLOAD16(Wlp + woff[qq] + k0, &Wl[ldsc[qq]]);
      }
    }
    __syncthreads();
    bf16x8 afh[4], afl[4];
    #pragma unroll
    for (int f = 0; f < 4; ++f) {
      afh[f] = *(const bf16x8*)&Ah[roffA[f]];
      afl[f] = *(const bf16x8*)&Al[roffA[f]];
    }
    #pragma unroll
    for (int fj = 0; fj < 4; ++fj) {
      bf16x8 wfh = *(const bf16x8*)&Wh[roffW[fj]];
      bf16x8 wfl = *(const bf16x8*)&Wl[roffW[fj]];
      #pragma unroll
      for (int fi = 0; fi < 4; ++fi) {
        acc[fi][fj] = __builtin_amdgcn_mfma_f32_16x16x32_bf16(afh[fi], wfh, acc[fi][fj], 0, 0, 0);
        acc[fi][fj] = __builtin_amdgcn_mfma_f32_16x16x32_bf16(afh[fi], wfl, acc[fi][fj], 0, 0, 0);
        acc[fi][fj] = __builtin_amdgcn_mfma_f32_16x16x32_bf16(afl[fi], wfh, acc[fi][fj], 0, 0, 0);
      }
    }
  }
  float* P = partial + (long)(dir * NSPL + kz) * (B_SZ * L_SEQ) * 80;
  const int fcol = lane & 15, rgrp = lane >> 4;
  #pragma unroll
  for (int fi = 0; fi < 4; ++fi) {
    #pragma unroll
    for (int j = 0; j < 4; ++j) {
      int row = m0 + wr * 64 + fi * 16 + rgrp * 4 + j;
      #pragma unroll
      for (int fj = 0; fj < 4; ++fj) {
        int n = wc * 64 + fj * 16 + fcol;
        if (n < 80) P[(long)row * 80 + n] = acc[fi][fj][j];
      }
    }
  }
}

__global__ __launch_bounds__(256) void xproj_reduce(
    const float* __restrict__ partial, float* __restrict__ dbl)
{
  long idx = (long)blockIdx.x * 256 + threadIdx.x;
  const long plane = (long)B_SZ * L_SEQ * 80;
  long dir = idx / plane;
  long rc = idx % plane;
  const float* P = partial + dir * NSPL * plane + rc;
  float s = 0.f;
  #pragma unroll
  for (int z = 0; z < NSPL; ++z) s += P[z * plane];
  dbl[idx] = s;
}

// -------- out_proj: all-plane MFMA; split-(dir,K); GLOAD16 staging --------
__global__ __launch_bounds__(256) void gemm_outproj_pl(
    const unsigned short* __restrict__ yh, const unsigned short* __restrict__ yl,
    const unsigned short* __restrict__ o0h, const unsigned short* __restrict__ o0l,
    const unsigned short* __restrict__ o1h, const unsigned short* __restrict__ o1l,
    float* __restrict__ partial)   // [4][4096][768], plane = dir*2+ks
{
  __shared__ unsigned short Ah[128 * 32], Al[128 * 32];
  __shared__ unsigned short Wh[128 * 32], Wl[128 * 32];
  const long S1 = (long)B_SZ * L_SEQ * D_INNER;
  const int tid = threadIdx.x;
  const int lane = tid & 63, w = tid >> 6;
  int bid = blockIdx.x;
  int swz = (bid & 7) * 96 + (bid >> 3);
  int dir = swz / 384;
  int r1 = swz - dir * 384;
  int ks = r1 / 192;
  int r2 = r1 - ks * 192;
  int mb = r2 / 6, nb = r2 - (r2 / 6) * 6;
  const int m0 = mb * 128, n0 = nb * 128;
  const int kbase = ks * (D_INNER / 2);
  const unsigned short* Ahp = yh + (long)dir * S1;
  const unsigned short* Alp = yl + (long)dir * S1;
  const unsigned short* Whp = dir ? o1h : o0h;
  const unsigned short* Wlp = dir ? o1l : o0l;
  const int ksl = (lane & 3) ^ ((lane >> 3) & 3);
  long aoff[2], woff[2];
  int ldsc[2];
  #pragma unroll
  for (int qq = 0; qq < 2; ++qq) {
    int cq = w * 2 + qq;
    int r = cq * 16 + (lane >> 2);
    int mr = m0 + r;
    int row = dir ? ((mr & ~(L_SEQ - 1)) | ((L_SEQ - 1) - (mr & (L_SEQ - 1)))) : mr;
    aoff[qq] = (long)row * D_INNER + 8 * ksl + kbase;
    woff[qq] = (long)(n0 + r) * D_INNER + 8 * ksl + kbase;
    ldsc[qq] = cq * 512;
  }
  f32x4 acc[4][4];
  #pragma unroll
  for (int i = 0; i < 4; ++i)
    #pragma unroll
    for (int j = 0; j < 4; ++j) acc[i][j] = (f32x4){0.f, 0.f, 0.f, 0.f};
  const int fr = lane & 15, sl = lane >> 4;
  const int wr = w >> 1, wc = w & 1;
  int roffA[4], roffW[4];
  #pragma unroll
  for (int f = 0; f < 4; ++f) {
    int rA = wr * 64 + f * 16 + fr;
    roffA[f] = rA * 32 + ((sl ^ ((rA >> 1) & 3)) * 8);
    int rW = wc * 64 + f * 16 + fr;
    roffW[f] = rW * 32 + ((sl ^ ((rW >> 1) & 3)) * 8);
  }
  for (int k0 = 0; k0 < D_INNER / 2; k0 += 32) {
    __syncthreads();
    #pragma unroll
    for (int qq = 0; qq < 2; ++qq) {
      GLOAD16(Ahp + aoff[qq] + k0, &Ah[ldsc[qq]]);
      GLOAD16(Alp + aoff[qq] + k0, &Al[ldsc[qq]]);
      GLOAD16(Whp + woff[qq] + k0, &Wh[ldsc[qq]]);
      GLOAD16(Wlp + woff[qq] + k0, &Wl[ldsc[qq]]);
    }
    __syncthreads();
    bf16x8 afh[4], afl[4];
    #pragma unroll
    for (int f = 0; f < 4; ++f) {
      afh[f] = *(const bf16x8*)&Ah[roffA[f]];
      afl[f] = *(const bf16x8*)&Al[roffA[f]];
    }
    #pragma unroll
    for (int fj = 0; fj < 4; ++fj) {
      bf16x8 wfh = *(const bf16x8*)&Wh[roffW[fj]];
      bf16x8 wfl = *(const bf16x8*)&Wl[roffW[fj]];
      #pragma unroll
      for (int fi = 0; fi < 4; ++fi) {
        acc[fi][fj] = __builtin_amdgcn_mfma_f32_16x16x32_bf16(afh[fi], wfh, acc[fi][fj], 0, 0, 0);
        acc[fi][fj] = __builtin_amdgcn_mfma_f32_16x16x32_bf16(afh[fi], wfl, acc[fi][fj], 0, 0, 0);
        acc[fi][fj] = __builtin_amdgcn_mfma_f32_16x16x32_bf16(afl[fi], wfh, acc[fi][fj], 0, 0, 0);
      }
    }
  }
  float* P = partial + (long)(dir * 2 + ks) * (B_SZ * L_SEQ) * D_MODEL;
  const int fcol = lane & 15, rgrp = lane >> 4;
  #pragma unroll
  for (int fi = 0; fi < 4; ++fi) {
    #pragma unroll
    for (int j = 0; j < 4; ++j) {
      int row = m0 + wr * 64 + fi * 16 + rgrp * 4 + j;
      #pragma unroll
      for (int fj = 0; fj < 4; ++fj) {
        int n = n0 + wc * 64 + fj * 16 + fcol;
        P[(long)row * D_MODEL + n] = acc[fi][fj][j];
      }
    }
  }
}

__global__ __launch_bounds__(256) void outproj_reduce(
    const float* __restrict__ partial, float* __restrict__ out)
{
  long i = (long)blockIdx.x * 256 + threadIdx.x;   // float4 index
  const long plane4 = (long)B_SZ * L_SEQ * D_MODEL / 4;  // 786432
  float4 a = ((const float4*)partial)[i];
  float4 b = ((const float4*)partial)[i + plane4];
  float4 c = ((const float4*)partial)[i + 2 * plane4];
  float4 d = ((const float4*)partial)[i + 3 * plane4];
  float4 s;
  s.x = (a.x + b.x) + (c.x + d.x);
  s.y = (a.y + b.y) + (c.y + d.y);
  s.z = (a.z + b.z) + (c.z + d.z);
  s.w = (a.w + b.w) + (c.w + d.w);
  ((float4*)out)[i] = s;
}

// -------- causal depthwise conv + bias + silu -> bf16 hi/lo planes --------
__global__ __launch_bounds__(256) void conv_silu_pl(
    const float* __restrict__ xpre,
    const float* __restrict__ w_f, const float* __restrict__ b_f,
    const float* __restrict__ w_r, const float* __restrict__ b_r,
    unsigned short* __restrict__ xh, unsigned short* __restrict__ xl)
{
  long i4 = (long)blockIdx.x * 256 + threadIdx.x;
  const long total4 = 2L * B_SZ * L_SEQ * D_INNER / 4;
  if (i4 >= total4) return;
  long idx = i4 * 4;
  int d0 = (int)(idx % D_INNER);
  long r = idx / D_INNER;
  int t = (int)(r & (L_SEQ - 1));
  const float* w  = (r >> 12) ? w_r : w_f;
  const float* cb = (r >> 12) ? b_r : b_f;
  float4 a = *(const float4*)&cb[d0];
  float4 wc[4];
  #pragma unroll
  for (int i = 0; i < 4; ++i) wc[i] = *(const float4*)&w[(d0 + i) * 4];
  #pragma unroll
  for (int k = 0; k < 4; ++k) {
    if (t - 3 + k >= 0) {
      float4 xv = *(const float4*)&xpre[(r - 3 + k) * D_INNER + d0];
      a.x = fmaf(((const float*)&wc[0])[k], xv.x, a.x);
      a.y = fmaf(((const float*)&wc[1])[k], xv.y, a.y);
      a.z = fmaf(((const float*)&wc[2])[k], xv.z, a.z);
      a.w = fmaf(((const float*)&wc[3])[k], xv.w, a.w);
    }
  }
  float vv[4] = {siluf(a.x), siluf(a.y), siluf(a.z), siluf(a.w)};
  unsigned short h4[4], l4[4];
  #pragma unroll
  for (int e = 0; e < 4; ++e) {
    unsigned short hv = f2bf_rn(vv[e]);
    h4[e] = hv;
    l4[e] = f2bf_rn(vv[e] - bf2f(hv));
  }
  uint2 ph, pl;
  ph.x = (unsigned)h4[0] | ((unsigned)h4[1] << 16);
  ph.y = (unsigned)h4[2] | ((unsigned)h4[3] << 16);
  pl.x = (unsigned)l4[0] | ((unsigned)l4[1] << 16);
  pl.y = (unsigned)l4[2] | ((unsigned)l4[3] << 16);
  *(uint2*)&xh[idx] = ph;
  *(uint2*)&xl[idx] = pl;
}

// -------- fused dtproj + selective-scan pass 1 (local S, P) ---------------
__global__ __launch_bounds__(256) void scan_mega1(
    const unsigned short* __restrict__ xh, const unsigned short* __restrict__ xl,
    const float* __restrict__ dbl,
    const float* __restrict__ dtw_f, const float* __restrict__ dtw_r,
    const float* __restrict__ dtb_f, const float* __restrict__ dtb_r,
    const float* __restrict__ A_log_f, const float* __restrict__ A_log_r,
    float* __restrict__ stateS, float* __restrict__ stateP)
{
  const int tid = threadIdx.x;
  const int chunk = blockIdx.x / NDG;
  const int d = (blockIdx.x % NDG) * 256 + tid;
  const int b = blockIdx.y, dir = blockIdx.z;
  const float* A_log = dir ? A_log_r : A_log_f;
  const float* dtw   = dir ? dtw_r : dtw_f;
  const float dtbv   = (dir ? dtb_r : dtb_f)[d];
  float wreg[48];
  #pragma unroll
  for (int q = 0; q < 12; ++q)
    *(float4*)&wreg[q * 4] = *(const float4*)&dtw[d * DT_RANK + q * 4];
  float Arow[D_STATE];
  #pragma unroll
  for (int n = 0; n < D_STATE; ++n) Arow[n] = -expf(A_log[d * D_STATE + n]);
  float h[D_STATE], P[D_STATE];
  #pragma unroll
  for (int n = 0; n < D_STATE; ++n) { h[n] = 0.f; P[n] = 1.f; }
  const long rowbase = ((long)dir * B_SZ + b) * L_SEQ + (long)chunk * TC;
  for (int tj = 0; tj < TC; ++tj) {
    const float* br = dbl + (rowbase + tj) * 80;
    float dtacc = 0.f;
    #pragma unroll
    for (int q = 0; q < 12; ++q) {
      float4 v = *(const float4*)(br + q * 4);
      dtacc = fmaf(v.x, wreg[q * 4 + 0], dtacc);
      dtacc = fmaf(v.y, wreg[q * 4 + 1], dtacc);
      dtacc = fmaf(v.z, wreg[q * 4 + 2], dtacc);
      dtacc = fmaf(v.w, wreg[q * 4 + 3], dtacc);
    }
    float dtv = softplusf(dtacc + dtbv);
    long off = (rowbase + tj) * D_INNER + d;
    float xv = bf2f(xh[off]) + bf2f(xl[off]);
    float dtx = dtv * xv;
    float bc[D_STATE];
    #pragma unroll
    for (int q = 0; q < 4; ++q)
      *(float4*)&bc[q * 4] = *(const float4*)(br + 48 + q * 4);
    #pragma unroll
    for (int n = 0; n < D_STATE; ++n) {
      float dA = __expf(dtv * Arow[n]);
      P[n] *= dA;
      h[n] = fmaf(h[n], dA, dtx * bc[n]);
    }
  }
  long base = ((((long)dir * B_SZ + b) * NC + chunk) * D_INNER + d) * D_STATE;
  #pragma unroll
  for (int n = 0; n < D_STATE; ++n) { stateS[base + n] = h[n]; stateP[base + n] = P[n]; }
}

__global__ __launch_bounds__(256) void scan_fix(
    float* __restrict__ stateS, const float* __restrict__ stateP)
{
  const long idx = (long)blockIdx.x * 256 + threadIdx.x;
  const int DN = D_INNER * D_STATE;
  const long dirb = idx / DN;
  const int dn = (int)(idx % DN);
  long base = dirb * NC * DN + dn;
  float h = 0.f;
  for (int c = 0; c < NC; ++c) {
    long o = base + (long)c * DN;
    float S = stateS[o];
    float Pc = stateP[o];
    stateS[o] = h;
    h = fmaf(h, Pc, S);
  }
}

// -------- fused dtproj + scan pass 2 + gating + y->bf16 planes ------------
__global__ __launch_bounds__(256) void scan_mega2(
    const unsigned short* __restrict__ xh, const unsigned short* __restrict__ xl,
    const float* __restrict__ dbl, const float* __restrict__ z,
    const float* __restrict__ dtw_f, const float* __restrict__ dtw_r,
    const float* __restrict__ dtb_f, const float* __restrict__ dtb_r,
    const float* __restrict__ A_log_f, const float* __restrict__ A_log_r,
    const float* __restrict__ Ds_f, const float* __restrict__ Ds_r,
    const float* __restrict__ stateS,
    unsigned short* __restrict__ yh, unsigned short* __restrict__ yl)
{
  const int tid = threadIdx.x;
  const int chunk = blockIdx.x / NDG;
  const int d = (blockIdx.x % NDG) * 256 + tid;
  const int b = blockIdx.y, dir = blockIdx.z;
  const float* A_log = dir ? A_log_r : A_log_f;
  const float* dtw   = dir ? dtw_r : dtw_f;
  const float dtbv   = (dir ? dtb_r : dtb_f)[d];
  const float Dd     = (dir ? Ds_r : Ds_f)[d];
  float wreg[48];
  #pragma unroll
  for (int q = 0; q < 12; ++q)
    *(float4*)&wreg[q * 4] = *(const float4*)&dtw[d * DT_RANK + q * 4];
  float Arow[D_STATE];
  #pragma unroll
  for (int n = 0; n < D_STATE; ++n) Arow[n] = -expf(A_log[d * D_STATE + n]);
  float h[D_STATE];
  long sbase = ((((long)dir * B_SZ + b) * NC + chunk) * D_INNER + d) * D_STATE;
  #pragma unroll
  for (int n = 0; n < D_STATE; ++n) h[n] = stateS[sbase + n];
  const long rowbase = ((long)dir * B_SZ + b) * L_SEQ + (long)chunk * TC;
  for (int tj = 0; tj < TC; ++tj) {
    const float* br = dbl + (rowbase + tj) * 80;
    float dtacc = 0.f;
    #pragma unroll
    for (int q = 0; q < 12; ++q) {
      float4 v = *(const float4*)(br + q * 4);
      dtacc = fmaf(v.x, wreg[q * 4 + 0], dtacc);
      dtacc = fmaf(v.y, wreg[q * 4 + 1], dtacc);
      dtacc = fmaf(v.z, wreg[q * 4 + 2], dtacc);
      dtacc = fmaf(v.w, wreg[q * 4 + 3], dtacc);
    }
    float dtv = softplusf(dtacc + dtbv);
    long off = (rowbase + tj) * D_INNER + d;
    float xv = bf2f(xh[off]) + bf2f(xl[off]);
    float zv = z[off];
    float dtx = dtv * xv;
    float bc[2 * D_STATE];
    #pragma unroll
    for (int q = 0; q < 8; ++q)
      *(float4*)&bc[q * 4] = *(const float4*)(br + 48 + q * 4);
    float y = 0.f;
    #pragma unroll
    for (int n = 0; n < D_STATE; ++n) {
      float dA = __expf(dtv * Arow[n]);
      h[n] = fmaf(h[n], dA, dtx * bc[n]);
      y = fmaf(h[n], bc[16 + n], y);
    }
    y = fmaf(xv, Dd, y);
    y *= siluf(zv);
    unsigned short hv = f2bf_rn(y);
    yh[off] = hv;
    yl[off] = f2bf_rn(y - bf2f(hv));
  }
}

extern "C" void kernel_launch(void* const* d_in, const int* in_sizes, int n_in,
                              void* d_out, int out_size, void* d_ws, size_t ws_size,
                              hipStream_t stream) {
  const float* h        = (const float*)d_in[0];
  const float* in_proj[2] = {(const float*)d_in[1], (const float*)d_in[10]};
  const float* conv_w[2]  = {(const float*)d_in[2], (const float*)d_in[11]};
  const float* conv_b[2]  = {(const float*)d_in[3], (const float*)d_in[12]};
  const float* xproj[2]   = {(const float*)d_in[4], (const float*)d_in[13]};
  const float* dtw[2]     = {(const float*)d_in[5], (const float*)d_in[14]};
  const float* dtb[2]     = {(const float*)d_in[6], (const float*)d_in[15]};
  const float* A_log[2]   = {(const float*)d_in[7], (const float*)d_in[16]};
  const float* Dsk[2]     = {(const float*)d_in[8], (const float*)d_in[17]};
  const float* outp[2]    = {(const float*)d_in[9], (const float*)d_in[18]};
  float* out = (float*)d_out;
  float* ws = (float*)d_ws;

  const long S1 = (long)B_SZ * L_SEQ * D_INNER;   // 6,291,456
  const int M = B_SZ * L_SEQ;                     // 4096
  float* xpre  = ws;                 // [2][4096][1536]: x-preconv, then yh/yl planes
  float* zbuf  = ws + 2 * S1;        // z
  float* xconv = ws + 4 * S1;        // xh/xl planes, then out_proj partials
  float* dbl   = ws + 6 * S1;        // xproj-W planes (phase A), then [2][4096][80]
  float* base4 = dbl + 2L * M * 80;

  // bf16 hi/lo planes (phase A); scan states / xproj partials overlay later
  unsigned short* hh  = (unsigned short*)base4;             // 3,145,728 each
  unsigned short* hl  = hh + 3145728;
  unsigned short* w0h = hl + 3145728;                       // 2,359,296 each
  unsigned short* w0l = w0h + 2359296;
  unsigned short* w1h = w0l + 2359296;
  unsigned short* w1l = w1h + 2359296;
  unsigned short* o0h = w1l + 2359296;                      // 1,179,648 each (live till end)
  unsigned short* o0l = o0h + 1179648;
  unsigned short* o1h = o0l + 1179648;
  unsigned short* o1l = o1h + 1179648;
  float* xpartial = base4;           // xproj partials overlay hh/hl (dead after in_proj)
  float* stS = base4;                // 3.15M fl
  float* stP = stS + 3145728;        // 3.15M fl (ends before o-planes)
  // xproj weight planes live in the dbl region (dead until xproj_reduce writes it)
  unsigned short* xw0h = (unsigned short*)dbl;              // 122,880 each (80x1536)
  unsigned short* xw0l = xw0h + 122880;
  unsigned short* xw1h = xw0l + 122880;
  unsigned short* xw1l = xw1h + 122880;
  // conv-output x planes fill the xconv region (4*S1 ushorts = 2*S1 floats)
  unsigned short* xph = (unsigned short*)xconv;             // [2][4096][1536]
  unsigned short* xpl = xph + 2 * S1;
  // y planes fill the xpre region
  unsigned short* yh = (unsigned short*)xpre;               // [2][4096][1536]
  unsigned short* yl = yh + 2 * S1;
  float* opartial = xconv;           // [4][4096][768] = 12.58M fl (x planes dead after mega2)

  dim3 blk(256);

  // 0. pre-convert h + all GEMM weights (incl. xproj W) to bf16 hi/lo planes
  cvt_all<<<dim3(10224), blk, 0, stream>>>(
      h, hh, hl, in_proj[0], w0h, w0l, in_proj[1], w1h, w1l,
      outp[0], o0h, o0l, outp[1], o1h, o1l,
      xproj[0], xw0h, xw0l, xproj[1], xw1h, xw1l);

  // 1. in_proj (both dirs) -> x (pre-conv, fp32) and z
  gemm_inproj<<<dim3(1536), blk, 0, stream>>>(hh, hl, w0h, w0l, w1h, w1l, xpre, zbuf);

  // 2. conv + silu -> x bf16 hi/lo planes
  conv_silu_pl<<<dim3((unsigned)(2 * S1 / 4 / 256)), blk, 0, stream>>>(
      xpre, conv_w[0], conv_b[0], conv_w[1], conv_b[1], xph, xpl);

  // 3. xproj (plane MFMA, split-K x4, 256 blocks) -> partials -> dbl
  xproj_mfma<<<dim3(256), blk, 0, stream>>>(xph, xpl, xw0h, xw0l, xw1h, xw1l, xpartial);
  xproj_reduce<<<dim3((unsigned)(2L * M * 80 / 256)), blk, 0, stream>>>(xpartial, dbl);

  // 4+5. fused dtproj + chunked scan
  {
    dim3 grid1(NC * NDG, B_SZ, 2);
    scan_mega1<<<grid1, blk, 0, stream>>>(xph, xpl, dbl,
        dtw[0], dtw[1], dtb[0], dtb[1], A_log[0], A_log[1], stS, stP);
    long nfix = 2L * B_SZ * D_INNER * D_STATE;
    scan_fix<<<dim3((unsigned)(nfix / 256)), blk, 0, stream>>>(stS, stP);
    scan_mega2<<<grid1, blk, 0, stream>>>(xph, xpl, dbl, zbuf,
        dtw[0], dtw[1], dtb[0], dtb[1], A_log[0], A_log[1],
        Dsk[0], Dsk[1], stS, yh, yl);
  }
  // 6. out_proj: split-(dir,K) all-plane MFMA + reduce
  gemm_outproj_pl<<<dim3(768), blk, 0, stream>>>(yh, yl, o0h, o0l, o1h, o1l, opartial);
  outproj_reduce<<<dim3((unsigned)(M * (long)D_MODEL / 4 / 256)), blk, 0, stream>>>(opartial, out);
}